// Round 1
// baseline (8894.936 us; speedup 1.0000x reference)
//
#include <hip/hip_runtime.h>
#include <hip/hip_bf16.h>
#include <math.h>

#define D_MODEL 1024
#define N_LAYER 2
#define D_STATE 16
#define D_CONV  4
#define D_INNER 2048
#define DT_RANK 64
#define VOCAB   32000
#define BATCH   2
#define SEQLEN  1024
#define TOKENS  (BATCH*SEQLEN)   // 2048

// ---------------- embedding gather ----------------
__global__ __launch_bounds__(256) void embed_kernel(const int* __restrict__ x,
                                                    const float* __restrict__ emb,
                                                    float* __restrict__ h) {
    int t = blockIdx.x;                 // token 0..2047
    int tok = x[t];
    const float4* src = (const float4*)(emb + (size_t)tok * D_MODEL);
    float4* dst = (float4*)(h + (size_t)t * D_MODEL);
    dst[threadIdx.x] = src[threadIdx.x];   // 256 threads * 4 floats = 1024
}

// ---------------- rmsnorm (one block per token row of 1024) ----------------
__global__ __launch_bounds__(256) void rmsnorm_kernel(const float* __restrict__ h,
                                                      const float* __restrict__ w,
                                                      float* __restrict__ u) {
    int t = blockIdx.x;
    const float4* hv = (const float4*)(h + (size_t)t * D_MODEL);
    float4 v = hv[threadIdx.x];
    float ss = v.x*v.x + v.y*v.y + v.z*v.z + v.w*v.w;
    #pragma unroll
    for (int off = 32; off > 0; off >>= 1) ss += __shfl_down(ss, off);
    __shared__ float red[4];
    int lane = threadIdx.x & 63, wid = threadIdx.x >> 6;
    if (lane == 0) red[wid] = ss;
    __syncthreads();
    float tot = red[0] + red[1] + red[2] + red[3];
    float scale = rsqrtf(tot * (1.0f / (float)D_MODEL) + 1e-5f);
    float4 wq = ((const float4*)w)[threadIdx.x];
    float4 o;
    o.x = v.x * scale * wq.x;
    o.y = v.y * scale * wq.y;
    o.z = v.z * scale * wq.z;
    o.w = v.w * scale * wq.w;
    ((float4*)(u + (size_t)t * D_MODEL))[threadIdx.x] = o;
}

// ---------------- generic tiled f32 GEMM: C[M,N] (+)= A[M,K(lda)] * W[N,K]^T ----
// block = 256 threads (16x16), tile 64x64, K-tile 16, 4x4 outputs/thread.
// M must be a multiple of 64; K a multiple of 16; N guarded.
__global__ __launch_bounds__(256) void gemm_f32(const float* __restrict__ A, int lda,
                                                const float* __restrict__ W,
                                                float* __restrict__ C,
                                                int M, int N, int K, int acc) {
    __shared__ float As[16][64];
    __shared__ float Bs[16][64];
    int tx = threadIdx.x & 15;
    int ty = threadIdx.x >> 4;
    int rowBase = blockIdx.y * 64;
    int colBase = blockIdx.x * 64;
    float accr[4][4] = {};
    int lc = tx;           // k within tile
    int lr = ty;           // row/col within tile, step 16
    for (int k0 = 0; k0 < K; k0 += 16) {
        #pragma unroll
        for (int i = 0; i < 4; ++i) {
            int r = rowBase + lr + 16 * i;
            As[lc][lr + 16 * i] = A[(size_t)r * lda + k0 + lc];
        }
        #pragma unroll
        for (int i = 0; i < 4; ++i) {
            int n = colBase + lr + 16 * i;
            float v = 0.f;
            if (n < N) v = W[(size_t)n * K + k0 + lc];
            Bs[lc][lr + 16 * i] = v;
        }
        __syncthreads();
        #pragma unroll
        for (int kk = 0; kk < 16; ++kk) {
            float a[4], b[4];
            #pragma unroll
            for (int i = 0; i < 4; ++i) a[i] = As[kk][ty + 16 * i];
            #pragma unroll
            for (int j = 0; j < 4; ++j) b[j] = Bs[kk][tx + 16 * j];
            #pragma unroll
            for (int i = 0; i < 4; ++i)
                #pragma unroll
                for (int j = 0; j < 4; ++j)
                    accr[i][j] += a[i] * b[j];
        }
        __syncthreads();
    }
    #pragma unroll
    for (int i = 0; i < 4; ++i) {
        int r = rowBase + ty + 16 * i;
        #pragma unroll
        for (int j = 0; j < 4; ++j) {
            int n = colBase + tx + 16 * j;
            if (n < N) {
                size_t idx = (size_t)r * N + n;
                C[idx] = acc ? (C[idx] + accr[i][j]) : accr[i][j];
            }
        }
    }
}

// ---------------- causal depthwise conv (k=4) + bias + silu ----------------
// xi = xz[:, 0:2048]; out xc[t,d]
__global__ __launch_bounds__(256) void conv_silu_kernel(const float* __restrict__ xz,
                                                        const float* __restrict__ cw,
                                                        const float* __restrict__ cb,
                                                        float* __restrict__ xc) {
    int d = blockIdx.x * 256 + threadIdx.x;  // 0..2047
    int l = blockIdx.y;                      // 0..1023
    int b = blockIdx.z;                      // 0..1
    float acc = cb[d];
    #pragma unroll
    for (int j = 0; j < 4; ++j) {
        int l2 = l - 3 + j;
        if (l2 >= 0) {
            size_t t = (size_t)b * SEQLEN + l2;
            acc += cw[d * 4 + j] * xz[t * (2 * D_INNER) + d];
        }
    }
    float s = acc / (1.0f + expf(-acc));    // silu
    xc[((size_t)b * SEQLEN + l) * D_INNER + d] = s;
}

// ---------------- fused softplus + selective scan + gate ----------------
// one thread per (b, d) channel; sequential over L with 16-wide state.
__global__ __launch_bounds__(256) void scan_kernel(const float* __restrict__ dtp,   // [T,2048] pre-bias/softplus
                                                   const float* __restrict__ dt_bias,// [2048]
                                                   const float* __restrict__ dbl,   // [T,96]
                                                   const float* __restrict__ xc,    // [T,2048]
                                                   const float* __restrict__ xz,    // [T,4096] (z = cols 2048..4095)
                                                   const float* __restrict__ A_log, // [2048,16]
                                                   const float* __restrict__ Dp,    // [2048]
                                                   float* __restrict__ y) {         // [T,2048]
    int d = blockIdx.x * 256 + threadIdx.x;  // 0..2047
    int b = blockIdx.y;                      // 0..1
    float A[D_STATE];
    #pragma unroll
    for (int n = 0; n < D_STATE; ++n) A[n] = -expf(A_log[d * D_STATE + n]);
    float Dv = Dp[d];
    float bias = dt_bias[d];
    float st[D_STATE];
    #pragma unroll
    for (int n = 0; n < D_STATE; ++n) st[n] = 0.f;
    for (int l = 0; l < SEQLEN; ++l) {
        size_t t = (size_t)b * SEQLEN + l;
        float dtv = dtp[t * D_INNER + d] + bias;
        dtv = (dtv > 20.f) ? dtv : log1pf(expf(dtv));   // softplus
        float xcv = xc[t * D_INNER + d];
        float dx = dtv * xcv;
        const float* Brow = dbl + t * 96 + DT_RANK;          // 16
        const float* Crow = dbl + t * 96 + DT_RANK + D_STATE;// 16
        float acc = 0.f;
        #pragma unroll
        for (int n = 0; n < D_STATE; ++n) {
            float a = expf(dtv * A[n]);
            st[n] = a * st[n] + dx * Brow[n];
            acc += st[n] * Crow[n];
        }
        acc += xcv * Dv;
        float zv = xz[t * (2 * D_INNER) + D_INNER + d];
        float sz = zv / (1.0f + expf(-zv));
        y[t * D_INNER + d] = acc * sz;
    }
}

extern "C" void kernel_launch(void* const* d_in, const int* in_sizes, int n_in,
                              void* d_out, int out_size, void* d_ws, size_t ws_size,
                              hipStream_t stream) {
    const int*   x          = (const int*)  d_in[0];
    const float* emb        = (const float*)d_in[1];
    const float* norm_w     = (const float*)d_in[2];
    const float* in_proj_w  = (const float*)d_in[3];
    const float* conv_w     = (const float*)d_in[4];
    const float* conv_b     = (const float*)d_in[5];
    const float* x_proj_w   = (const float*)d_in[6];
    const float* dt_proj_w  = (const float*)d_in[7];
    const float* dt_bias    = (const float*)d_in[8];
    const float* A_log      = (const float*)d_in[9];
    const float* Dp         = (const float*)d_in[10];
    const float* out_proj_w = (const float*)d_in[11];
    const float* fnorm_w    = (const float*)d_in[12];
    float* out = (float*)d_out;
    float* ws  = (float*)d_ws;

    // small scratch in ws (~17.5 MB)
    float* h   = ws;                    // [2048,1024]
    float* u   = ws + 2097152;          // [2048,1024]
    float* dbl = ws + 4194304;          // [2048,96]

    // large intermediates aliased into d_out (dead before final vocab GEMM,
    // which overwrites every element of d_out):
    float* xz  = out;                   // [2048,4096]  8,388,608 f
    float* xc  = out + 8388608;         // [2048,2048]  4,194,304 f
    float* dtp = out + 12582912;        // [2048,2048]  4,194,304 f
    float* y   = out + 16777216;        // [2048,2048]  4,194,304 f

    embed_kernel<<<TOKENS, 256, 0, stream>>>(x, emb, h);

    for (int layer = 0; layer < N_LAYER; ++layer) {
        rmsnorm_kernel<<<TOKENS, 256, 0, stream>>>(h, norm_w + layer * D_MODEL, u);
        gemm_f32<<<dim3(4096/64, TOKENS/64), 256, 0, stream>>>(
            u, D_MODEL, in_proj_w + (size_t)layer * 2 * D_INNER * D_MODEL,
            xz, TOKENS, 2 * D_INNER, D_MODEL, 0);
        conv_silu_kernel<<<dim3(D_INNER/256, SEQLEN, BATCH), 256, 0, stream>>>(
            xz, conv_w + (size_t)layer * D_INNER * D_CONV, conv_b + layer * D_INNER, xc);
        gemm_f32<<<dim3(2, TOKENS/64), 256, 0, stream>>>(
            xc, D_INNER, x_proj_w + (size_t)layer * 96 * D_INNER,
            dbl, TOKENS, 96, D_INNER, 0);
        gemm_f32<<<dim3(D_INNER/64, TOKENS/64), 256, 0, stream>>>(
            dbl, 96, dt_proj_w + (size_t)layer * D_INNER * DT_RANK,
            dtp, TOKENS, D_INNER, DT_RANK, 0);
        scan_kernel<<<dim3(D_INNER/256, BATCH), 256, 0, stream>>>(
            dtp, dt_bias + layer * D_INNER, dbl, xc, xz,
            A_log + (size_t)layer * D_INNER * D_STATE, Dp + layer * D_INNER, y);
        gemm_f32<<<dim3(D_MODEL/64, TOKENS/64), 256, 0, stream>>>(
            y, D_INNER, out_proj_w + (size_t)layer * D_MODEL * D_INNER,
            h, TOKENS, D_MODEL, D_INNER, 1);
    }

    rmsnorm_kernel<<<TOKENS, 256, 0, stream>>>(h, fnorm_w, u);
    gemm_f32<<<dim3(VOCAB/64, TOKENS/64), 256, 0, stream>>>(
        u, D_MODEL, emb, out, TOKENS, VOCAB, D_MODEL, 0);
}

// Round 2
// 3600.320 us; speedup vs baseline: 2.4706x; 2.4706x over previous
//
#include <hip/hip_runtime.h>
#include <hip/hip_bf16.h>
#include <math.h>

#define D_MODEL 1024
#define N_LAYER 2
#define D_STATE 16
#define D_CONV  4
#define D_INNER 2048
#define DT_RANK 64
#define VOCAB   32000
#define BATCH   2
#define SEQLEN  1024
#define TOKENS  (BATCH*SEQLEN)   // 2048

typedef __hip_bfloat16 bf16;
typedef __bf16 bf16x8 __attribute__((ext_vector_type(8)));
typedef float f32x4 __attribute__((ext_vector_type(4)));

__device__ inline void gld_lds16(const bf16* g, bf16* l) {
    __builtin_amdgcn_global_load_lds(
        (const __attribute__((address_space(1))) void*)g,
        (__attribute__((address_space(3))) void*)l, 16, 0, 0);
}

// ---------------- embedding gather ----------------
__global__ __launch_bounds__(256) void embed_kernel(const int* __restrict__ x,
                                                    const float* __restrict__ emb,
                                                    float* __restrict__ h) {
    int t = blockIdx.x;
    int tok = x[t];
    const float4* src = (const float4*)(emb + (size_t)tok * D_MODEL);
    float4* dst = (float4*)(h + (size_t)t * D_MODEL);
    dst[threadIdx.x] = src[threadIdx.x];
}

// ---------------- rmsnorm -> bf16 output ----------------
__global__ __launch_bounds__(256) void rmsnorm_bf16(const float* __restrict__ h,
                                                    const float* __restrict__ w,
                                                    bf16* __restrict__ u) {
    int t = blockIdx.x;
    const float4* hv = (const float4*)(h + (size_t)t * D_MODEL);
    float4 v = hv[threadIdx.x];
    float ss = v.x*v.x + v.y*v.y + v.z*v.z + v.w*v.w;
    #pragma unroll
    for (int off = 32; off > 0; off >>= 1) ss += __shfl_down(ss, off);
    __shared__ float red[4];
    int lane = threadIdx.x & 63, wid = threadIdx.x >> 6;
    if (lane == 0) red[wid] = ss;
    __syncthreads();
    float tot = red[0] + red[1] + red[2] + red[3];
    float scale = rsqrtf(tot * (1.0f / (float)D_MODEL) + 1e-5f);
    float4 wq = ((const float4*)w)[threadIdx.x];
    size_t o = (size_t)t * D_MODEL + threadIdx.x * 4;
    u[o+0] = __float2bfloat16(v.x * scale * wq.x);
    u[o+1] = __float2bfloat16(v.y * scale * wq.y);
    u[o+2] = __float2bfloat16(v.z * scale * wq.z);
    u[o+3] = __float2bfloat16(v.w * scale * wq.w);
}

// ---------------- f32 -> bf16 convert (n multiple of 4) ----------------
__global__ __launch_bounds__(256) void f32_to_bf16(const float* __restrict__ s,
                                                   bf16* __restrict__ d, int n) {
    int i = (blockIdx.x * 256 + threadIdx.x) * 4;
    if (i < n) {
        float4 v = *(const float4*)(s + i);
        d[i+0] = __float2bfloat16(v.x);
        d[i+1] = __float2bfloat16(v.y);
        d[i+2] = __float2bfloat16(v.z);
        d[i+3] = __float2bfloat16(v.w);
    }
}

// ---------------- x_proj weight: [96][2048] -> padded bf16 [128][2048] ----------------
__global__ __launch_bounds__(256) void conv_xproj_pad(const float* __restrict__ s,
                                                      bf16* __restrict__ d) {
    int col = blockIdx.x * 256 + threadIdx.x;   // 0..2047
    int row = blockIdx.y;                       // 0..127
    int layer = blockIdx.z;
    float v = (row < 96) ? s[((size_t)layer * 96 + row) * D_INNER + col] : 0.f;
    d[((size_t)layer * 128 + row) * D_INNER + col] = __float2bfloat16(v);
}

// ---------------- bf16 MFMA GEMM: C[M,N] (+)= A[M,K] * W[N,K]^T ----------------
// 128x128 tile, BK=32, 256 threads = 4 waves (2x2), 64x64 per wave.
// Requirements: M mult of 128, K mult of 32, W has >= ceil(N/128)*128 rows,
// A rows 16B-aligned (lda mult of 8), store guarded by n < N.
__global__ __launch_bounds__(256) void gemm_bf16(
    const bf16* __restrict__ A, int lda,
    const bf16* __restrict__ W, int ldw,
    float* __restrict__ C, int ldc,
    int N, int K, int acc)
{
    __shared__ bf16 As[128*32];
    __shared__ bf16 Bs[128*32];
    const int tid  = threadIdx.x;
    const int wave = tid >> 6;
    const int lane = tid & 63;
    const int wr = wave >> 1, wc = wave & 1;
    const size_t rowBase = (size_t)blockIdx.y * 128;
    const size_t colBase = (size_t)blockIdx.x * 128;

    const int l4 = lane >> 2;          // 0..15 (row within 16-row chunk)
    const int k8 = (lane & 3) << 3;    // 0,8,16,24 (k offset)

    const bf16* aG0 = A + (rowBase + 32*wave      + l4) * (size_t)lda + k8;
    const bf16* aG1 = A + (rowBase + 32*wave + 16 + l4) * (size_t)lda + k8;
    const bf16* bG0 = W + (colBase + 32*wave      + l4) * (size_t)ldw + k8;
    const bf16* bG1 = W + (colBase + 32*wave + 16 + l4) * (size_t)ldw + k8;
    bf16* AsW = As + wave * 1024;
    bf16* BsW = Bs + wave * 1024;

    f32x4 accv[4][4];
    #pragma unroll
    for (int i = 0; i < 4; ++i)
        #pragma unroll
        for (int j = 0; j < 4; ++j)
            accv[i][j] = f32x4{0.f, 0.f, 0.f, 0.f};

    const int arow = wr*64 + (lane & 15);
    const int brow = wc*64 + (lane & 15);
    const int koff = (lane >> 4) << 3;
    const bf16* Ard = As + arow*32 + koff;
    const bf16* Brd = Bs + brow*32 + koff;

    for (int k0 = 0; k0 < K; k0 += 32) {
        gld_lds16(aG0 + k0, AsW);
        gld_lds16(aG1 + k0, AsW + 512);
        gld_lds16(bG0 + k0, BsW);
        gld_lds16(bG1 + k0, BsW + 512);
        __syncthreads();
        bf16x8 af[4], bv[4];
        #pragma unroll
        for (int i = 0; i < 4; ++i) af[i] = *(const bf16x8*)(Ard + i*16*32);
        #pragma unroll
        for (int j = 0; j < 4; ++j) bv[j] = *(const bf16x8*)(Brd + j*16*32);
        #pragma unroll
        for (int i = 0; i < 4; ++i)
            #pragma unroll
            for (int j = 0; j < 4; ++j)
                accv[i][j] = __builtin_amdgcn_mfma_f32_16x16x32_bf16(af[i], bv[j], accv[i][j], 0, 0, 0);
        __syncthreads();
    }

    const int cl = lane & 15;
    const int rg = (lane >> 4) * 4;
    #pragma unroll
    for (int i = 0; i < 4; ++i) {
        #pragma unroll
        for (int j = 0; j < 4; ++j) {
            int col = (int)colBase + wc*64 + j*16 + cl;
            if (col < N) {
                size_t base = (rowBase + wr*64 + i*16 + rg) * (size_t)ldc + col;
                #pragma unroll
                for (int r = 0; r < 4; ++r) {
                    size_t idx = base + (size_t)r * ldc;
                    C[idx] = acc ? C[idx] + accv[i][j][r] : accv[i][j][r];
                }
            }
        }
    }
}

// ---------------- causal depthwise conv (k=4) + bias + silu ----------------
__global__ __launch_bounds__(256) void conv_silu_kernel(const float* __restrict__ xz,
                                                        const float* __restrict__ cw,
                                                        const float* __restrict__ cb,
                                                        float* __restrict__ xcf,
                                                        bf16* __restrict__ xcb) {
    int d = blockIdx.x * 256 + threadIdx.x;
    int l = blockIdx.y;
    int b = blockIdx.z;
    float acc = cb[d];
    #pragma unroll
    for (int j = 0; j < 4; ++j) {
        int l2 = l - 3 + j;
        if (l2 >= 0) {
            size_t t = (size_t)b * SEQLEN + l2;
            acc += cw[d * 4 + j] * xz[t * (2 * D_INNER) + d];
        }
    }
    float s = acc / (1.0f + expf(-acc));
    size_t o = ((size_t)b * SEQLEN + l) * D_INNER + d;
    xcf[o] = s;
    xcb[o] = __float2bfloat16(s);
}

// ---------------- fused softplus + selective scan + gate ----------------
__global__ __launch_bounds__(256) void scan_kernel(const float* __restrict__ dtp,
                                                   const float* __restrict__ dt_bias,
                                                   const float* __restrict__ dbl,
                                                   const float* __restrict__ xc,
                                                   const float* __restrict__ xz,
                                                   const float* __restrict__ A_log,
                                                   const float* __restrict__ Dp,
                                                   bf16* __restrict__ y) {
    int d = blockIdx.x * 256 + threadIdx.x;
    int b = blockIdx.y;
    float A[D_STATE];
    #pragma unroll
    for (int n = 0; n < D_STATE; ++n) A[n] = -expf(A_log[d * D_STATE + n]);
    float Dv = Dp[d];
    float bias = dt_bias[d];
    float st[D_STATE];
    #pragma unroll
    for (int n = 0; n < D_STATE; ++n) st[n] = 0.f;
    for (int l = 0; l < SEQLEN; ++l) {
        size_t t = (size_t)b * SEQLEN + l;
        float dtv = dtp[t * D_INNER + d] + bias;
        dtv = (dtv > 20.f) ? dtv : log1pf(expf(dtv));
        float xcv = xc[t * D_INNER + d];
        float dx = dtv * xcv;
        const float* Brow = dbl + t * 96 + DT_RANK;
        const float* Crow = dbl + t * 96 + DT_RANK + D_STATE;
        float acc = 0.f;
        #pragma unroll
        for (int n = 0; n < D_STATE; ++n) {
            float a = expf(dtv * A[n]);
            st[n] = a * st[n] + dx * Brow[n];
            acc += st[n] * Crow[n];
        }
        acc += xcv * Dv;
        float zv = xz[t * (2 * D_INNER) + D_INNER + d];
        float sz = zv / (1.0f + expf(-zv));
        y[t * D_INNER + d] = __float2bfloat16(acc * sz);
    }
}

extern "C" void kernel_launch(void* const* d_in, const int* in_sizes, int n_in,
                              void* d_out, int out_size, void* d_ws, size_t ws_size,
                              hipStream_t stream) {
    const int*   x          = (const int*)  d_in[0];
    const float* emb        = (const float*)d_in[1];
    const float* norm_w     = (const float*)d_in[2];
    const float* in_proj_w  = (const float*)d_in[3];
    const float* conv_w     = (const float*)d_in[4];
    const float* conv_b     = (const float*)d_in[5];
    const float* x_proj_w   = (const float*)d_in[6];
    const float* dt_proj_w  = (const float*)d_in[7];
    const float* dt_bias    = (const float*)d_in[8];
    const float* A_log      = (const float*)d_in[9];
    const float* Dp         = (const float*)d_in[10];
    const float* out_proj_w = (const float*)d_in[11];
    const float* fnorm_w    = (const float*)d_in[12];
    float* out = (float*)d_out;

    // ---- d_out scratch layout (all dead before vocab GEMM writes logits) ----
    float* xz   = out;                   // [2048][4096]   8,388,608 f
    float* xc_f = out + 8388608;         // [2048][2048]   4,194,304 f
    float* dtp  = out + 12582912;        // [2048][2048]   4,194,304 f
    float* h    = out + 16777216;        // [2048][1024]   2,097,152 f
    float* dblf = out + 18874368;        // [2048][96]       196,608 f
    bf16* y_b    = (bf16*)(out + 19070976);  // [2048][2048] bf16
    bf16* xc_b   = (bf16*)(out + 21168128);  // [2048][2048] bf16
    bf16* dbl_b  = (bf16*)(out + 23265280);  // [2048][96]   bf16
    bf16* inpj_b = (bf16*)(out + 23363584);  // [2][4096][1024] bf16
    bf16* xpj_b  = (bf16*)(out + 27557888);  // [2][128][2048]  bf16 (padded 96->128)
    bf16* dtpj_b = (bf16*)(out + 27820032);  // [2][2048][64]   bf16
    bf16* otpj_b = (bf16*)(out + 27951104);  // [2][1024][2048] bf16
    // ends at f-offset 30,048,256 < 65,536,000

    // ---- ws layout (operands of vocab GEMM must not alias d_out) ----
    bf16* embc_b = (bf16*)d_ws;                  // [4096][1024] bf16 chunk (8.4 MB)
    bf16* u_b    = (bf16*)d_ws + 4194304;        // [2048][1024] bf16 (4.2 MB)

    // ---- weight conversions (per call; deterministic) ----
    f32_to_bf16<<<(2*2*D_INNER*D_MODEL/4 + 255)/256, 256, 0, stream>>>(in_proj_w,  inpj_b, 2*2*D_INNER*D_MODEL);
    conv_xproj_pad<<<dim3(D_INNER/256, 128, N_LAYER), 256, 0, stream>>>(x_proj_w, xpj_b);
    f32_to_bf16<<<(2*D_INNER*DT_RANK/4 + 255)/256, 256, 0, stream>>>(dt_proj_w,  dtpj_b, 2*D_INNER*DT_RANK);
    f32_to_bf16<<<(2*D_MODEL*D_INNER/4 + 255)/256, 256, 0, stream>>>(out_proj_w, otpj_b, 2*D_MODEL*D_INNER);

    embed_kernel<<<TOKENS, 256, 0, stream>>>(x, emb, h);

    for (int layer = 0; layer < N_LAYER; ++layer) {
        rmsnorm_bf16<<<TOKENS, 256, 0, stream>>>(h, norm_w + layer * D_MODEL, u_b);
        gemm_bf16<<<dim3(4096/128, TOKENS/128), 256, 0, stream>>>(
            u_b, D_MODEL, inpj_b + (size_t)layer * 2 * D_INNER * D_MODEL, D_MODEL,
            xz, 2 * D_INNER, 2 * D_INNER, D_MODEL, 0);
        conv_silu_kernel<<<dim3(D_INNER/256, SEQLEN, BATCH), 256, 0, stream>>>(
            xz, conv_w + (size_t)layer * D_INNER * D_CONV, conv_b + layer * D_INNER,
            xc_f, xc_b);
        gemm_bf16<<<dim3(1, TOKENS/128), 256, 0, stream>>>(
            xc_b, D_INNER, xpj_b + (size_t)layer * 128 * D_INNER, D_INNER,
            dblf, 96, 96, D_INNER, 0);
        f32_to_bf16<<<(TOKENS*96/4 + 255)/256, 256, 0, stream>>>(dblf, dbl_b, TOKENS*96);
        gemm_bf16<<<dim3(D_INNER/128, TOKENS/128), 256, 0, stream>>>(
            dbl_b, 96, dtpj_b + (size_t)layer * D_INNER * DT_RANK, DT_RANK,
            dtp, D_INNER, D_INNER, DT_RANK, 0);
        scan_kernel<<<dim3(D_INNER/256, BATCH), 256, 0, stream>>>(
            dtp, dt_bias + layer * D_INNER, dblf, xc_f, xz,
            A_log + (size_t)layer * D_INNER * D_STATE, Dp + layer * D_INNER, y_b);
        gemm_bf16<<<dim3(D_MODEL/128, TOKENS/128), 256, 0, stream>>>(
            y_b, D_INNER, otpj_b + (size_t)layer * D_MODEL * D_INNER, D_INNER,
            h, D_MODEL, D_MODEL, D_INNER, 1);
    }

    rmsnorm_bf16<<<TOKENS, 256, 0, stream>>>(h, fnorm_w, u_b);

    // ---- vocab GEMM in chunks; emb chunk staged bf16 in ws ----
    int n0 = 0;
    while (n0 < VOCAB) {
        int chunk = (VOCAB - n0 >= 4096) ? 4096 : (VOCAB - n0);   // 7x4096 + 3328
        f32_to_bf16<<<(chunk*D_MODEL/4 + 255)/256, 256, 0, stream>>>(
            emb + (size_t)n0 * D_MODEL, embc_b, chunk * D_MODEL);
        gemm_bf16<<<dim3(chunk/128, TOKENS/128), 256, 0, stream>>>(
            u_b, D_MODEL, embc_b, D_MODEL,
            out + n0, VOCAB, chunk, D_MODEL, 0);
        n0 += chunk;
    }
}

// Round 3
// 941.597 us; speedup vs baseline: 9.4467x; 3.8236x over previous
//
#include <hip/hip_runtime.h>
#include <hip/hip_bf16.h>
#include <math.h>

#define D_MODEL 1024
#define N_LAYER 2
#define D_STATE 16
#define D_CONV  4
#define D_INNER 2048
#define DT_RANK 64
#define VOCAB   32000
#define BATCH   2
#define SEQLEN  1024
#define TOKENS  (BATCH*SEQLEN)   // 2048
#define NC      32               // scan chunks
#define CL      32               // steps per chunk (SEQLEN/NC)

typedef __hip_bfloat16 bf16;
typedef __bf16 bf16x8 __attribute__((ext_vector_type(8)));
typedef float f32x4 __attribute__((ext_vector_type(4)));

__device__ inline void gld_lds16(const bf16* g, bf16* l) {
    __builtin_amdgcn_global_load_lds(
        (const __attribute__((address_space(1))) void*)g,
        (__attribute__((address_space(3))) void*)l, 16, 0, 0);
}

// ---------------- embedding gather ----------------
__global__ __launch_bounds__(256) void embed_kernel(const int* __restrict__ x,
                                                    const float* __restrict__ emb,
                                                    float* __restrict__ h) {
    int t = blockIdx.x;
    int tok = x[t];
    const float4* src = (const float4*)(emb + (size_t)tok * D_MODEL);
    float4* dst = (float4*)(h + (size_t)t * D_MODEL);
    dst[threadIdx.x] = src[threadIdx.x];
}

// ---------------- rmsnorm -> bf16 output ----------------
__global__ __launch_bounds__(256) void rmsnorm_bf16(const float* __restrict__ h,
                                                    const float* __restrict__ w,
                                                    bf16* __restrict__ u) {
    int t = blockIdx.x;
    const float4* hv = (const float4*)(h + (size_t)t * D_MODEL);
    float4 v = hv[threadIdx.x];
    float ss = v.x*v.x + v.y*v.y + v.z*v.z + v.w*v.w;
    #pragma unroll
    for (int off = 32; off > 0; off >>= 1) ss += __shfl_down(ss, off);
    __shared__ float red[4];
    int lane = threadIdx.x & 63, wid = threadIdx.x >> 6;
    if (lane == 0) red[wid] = ss;
    __syncthreads();
    float tot = red[0] + red[1] + red[2] + red[3];
    float scale = rsqrtf(tot * (1.0f / (float)D_MODEL) + 1e-5f);
    float4 wq = ((const float4*)w)[threadIdx.x];
    size_t o = (size_t)t * D_MODEL + threadIdx.x * 4;
    u[o+0] = __float2bfloat16(v.x * scale * wq.x);
    u[o+1] = __float2bfloat16(v.y * scale * wq.y);
    u[o+2] = __float2bfloat16(v.z * scale * wq.z);
    u[o+3] = __float2bfloat16(v.w * scale * wq.w);
}

// ---------------- f32 -> bf16 convert (n multiple of 4) ----------------
__global__ __launch_bounds__(256) void f32_to_bf16(const float* __restrict__ s,
                                                   bf16* __restrict__ d, int n) {
    int i = (blockIdx.x * 256 + threadIdx.x) * 4;
    if (i < n) {
        float4 v = *(const float4*)(s + i);
        d[i+0] = __float2bfloat16(v.x);
        d[i+1] = __float2bfloat16(v.y);
        d[i+2] = __float2bfloat16(v.z);
        d[i+3] = __float2bfloat16(v.w);
    }
}

// ---------------- x_proj weight: [96][2048] -> padded bf16 [128][2048] ----------------
__global__ __launch_bounds__(256) void conv_xproj_pad(const float* __restrict__ s,
                                                      bf16* __restrict__ d) {
    int col = blockIdx.x * 256 + threadIdx.x;
    int row = blockIdx.y;
    int layer = blockIdx.z;
    float v = (row < 96) ? s[((size_t)layer * 96 + row) * D_INNER + col] : 0.f;
    d[((size_t)layer * 128 + row) * D_INNER + col] = __float2bfloat16(v);
}

// ---------------- bf16 MFMA GEMM: C[M,N] (+)= A[M,K] * W[N,K]^T ----------------
__global__ __launch_bounds__(256) void gemm_bf16(
    const bf16* __restrict__ A, int lda,
    const bf16* __restrict__ W, int ldw,
    float* __restrict__ C, int ldc,
    int N, int K, int acc)
{
    __shared__ bf16 As[128*32];
    __shared__ bf16 Bs[128*32];
    const int tid  = threadIdx.x;
    const int wave = tid >> 6;
    const int lane = tid & 63;
    const int wr = wave >> 1, wc = wave & 1;
    const size_t rowBase = (size_t)blockIdx.y * 128;
    const size_t colBase = (size_t)blockIdx.x * 128;

    const int l4 = lane >> 2;
    const int k8 = (lane & 3) << 3;

    const bf16* aG0 = A + (rowBase + 32*wave      + l4) * (size_t)lda + k8;
    const bf16* aG1 = A + (rowBase + 32*wave + 16 + l4) * (size_t)lda + k8;
    const bf16* bG0 = W + (colBase + 32*wave      + l4) * (size_t)ldw + k8;
    const bf16* bG1 = W + (colBase + 32*wave + 16 + l4) * (size_t)ldw + k8;
    bf16* AsW = As + wave * 1024;
    bf16* BsW = Bs + wave * 1024;

    f32x4 accv[4][4];
    #pragma unroll
    for (int i = 0; i < 4; ++i)
        #pragma unroll
        for (int j = 0; j < 4; ++j)
            accv[i][j] = f32x4{0.f, 0.f, 0.f, 0.f};

    const int arow = wr*64 + (lane & 15);
    const int brow = wc*64 + (lane & 15);
    const int koff = (lane >> 4) << 3;
    const bf16* Ard = As + arow*32 + koff;
    const bf16* Brd = Bs + brow*32 + koff;

    for (int k0 = 0; k0 < K; k0 += 32) {
        gld_lds16(aG0 + k0, AsW);
        gld_lds16(aG1 + k0, AsW + 512);
        gld_lds16(bG0 + k0, BsW);
        gld_lds16(bG1 + k0, BsW + 512);
        __syncthreads();
        bf16x8 af[4], bv[4];
        #pragma unroll
        for (int i = 0; i < 4; ++i) af[i] = *(const bf16x8*)(Ard + i*16*32);
        #pragma unroll
        for (int j = 0; j < 4; ++j) bv[j] = *(const bf16x8*)(Brd + j*16*32);
        #pragma unroll
        for (int i = 0; i < 4; ++i)
            #pragma unroll
            for (int j = 0; j < 4; ++j)
                accv[i][j] = __builtin_amdgcn_mfma_f32_16x16x32_bf16(af[i], bv[j], accv[i][j], 0, 0, 0);
        __syncthreads();
    }

    const int cl = lane & 15;
    const int rg = (lane >> 4) * 4;
    #pragma unroll
    for (int i = 0; i < 4; ++i) {
        #pragma unroll
        for (int j = 0; j < 4; ++j) {
            int col = (int)colBase + wc*64 + j*16 + cl;
            if (col < N) {
                size_t base = (rowBase + wr*64 + i*16 + rg) * (size_t)ldc + col;
                #pragma unroll
                for (int r = 0; r < 4; ++r) {
                    size_t idx = base + (size_t)r * ldc;
                    C[idx] = acc ? C[idx] + accv[i][j][r] : accv[i][j][r];
                }
            }
        }
    }
}

// ---------------- causal depthwise conv (k=4) + bias + silu ----------------
__global__ __launch_bounds__(256) void conv_silu_kernel(const float* __restrict__ xz,
                                                        const float* __restrict__ cw,
                                                        const float* __restrict__ cb,
                                                        float* __restrict__ xcf,
                                                        bf16* __restrict__ xcb) {
    int d = blockIdx.x * 256 + threadIdx.x;
    int l = blockIdx.y;
    int b = blockIdx.z;
    float acc = cb[d];
    #pragma unroll
    for (int j = 0; j < 4; ++j) {
        int l2 = l - 3 + j;
        if (l2 >= 0) {
            size_t t = (size_t)b * SEQLEN + l2;
            acc += cw[d * 4 + j] * xz[t * (2 * D_INNER) + d];
        }
    }
    float s = acc / (1.0f + expf(-acc));
    size_t o = ((size_t)b * SEQLEN + l) * D_INNER + d;
    xcf[o] = s;
    xcb[o] = __float2bfloat16(s);
}

__device__ inline float softplusf(float v) {
    return (v > 20.f) ? v : log1pf(expf(v));
}

// ---------------- scan phase A: per-chunk summaries (zero init) ----------------
// aprod/sfin layout: [b][c][n][d]  -> (((b*NC + c)*D_STATE + n)*D_INNER + d)
__global__ __launch_bounds__(256) void scan_chunk(const float* __restrict__ dtp,
                                                  const float* __restrict__ dt_bias,
                                                  const float* __restrict__ dbl,
                                                  const float* __restrict__ xc,
                                                  const float* __restrict__ A_log,
                                                  float* __restrict__ aprod,
                                                  float* __restrict__ sfin) {
    int d = blockIdx.x * 256 + threadIdx.x;
    int c = blockIdx.y;
    int b = blockIdx.z;
    __shared__ float Bs[CL][D_STATE];
    for (int i = threadIdx.x; i < CL * D_STATE; i += 256) {
        int l = i >> 4, n = i & 15;
        Bs[l][n] = dbl[((size_t)b * SEQLEN + c * CL + l) * 96 + DT_RANK + n];
    }
    __syncthreads();
    float A[D_STATE];
    #pragma unroll
    for (int n = 0; n < D_STATE; ++n) A[n] = -expf(A_log[d * D_STATE + n]);
    float bias = dt_bias[d];
    float ap[D_STATE], st[D_STATE];
    #pragma unroll
    for (int n = 0; n < D_STATE; ++n) { ap[n] = 1.f; st[n] = 0.f; }
    for (int l = 0; l < CL; ++l) {
        size_t t = (size_t)b * SEQLEN + c * CL + l;
        float dtv = softplusf(dtp[t * D_INNER + d] + bias);
        float dx = dtv * xc[t * D_INNER + d];
        #pragma unroll
        for (int n = 0; n < D_STATE; ++n) {
            float a = expf(dtv * A[n]);
            st[n] = a * st[n] + dx * Bs[l][n];
            ap[n] *= a;
        }
    }
    #pragma unroll
    for (int n = 0; n < D_STATE; ++n) {
        size_t o = (((size_t)b * NC + c) * D_STATE + n) * D_INNER + d;
        aprod[o] = ap[n];
        sfin[o] = st[n];
    }
}

// ---------------- scan phase B: carry chunk-initial states ----------------
__global__ __launch_bounds__(256) void scan_carry(const float* __restrict__ aprod,
                                                  const float* __restrict__ sfin,
                                                  float* __restrict__ initS) {
    int idx = blockIdx.x * 256 + threadIdx.x;   // (b,n,d): b*16*2048 + n*2048 + d
    int d = idx & (D_INNER - 1);
    int n = (idx >> 11) & (D_STATE - 1);
    int b = idx >> 15;
    float st = 0.f;
    for (int c = 0; c < NC; ++c) {
        size_t o = (((size_t)b * NC + c) * D_STATE + n) * D_INNER + d;
        initS[o] = st;
        st = aprod[o] * st + sfin[o];
    }
}

// ---------------- scan phase C: recompute with true init, emit gated y ----------------
__global__ __launch_bounds__(256) void scan_emit(const float* __restrict__ dtp,
                                                 const float* __restrict__ dt_bias,
                                                 const float* __restrict__ dbl,
                                                 const float* __restrict__ xc,
                                                 const float* __restrict__ xz,
                                                 const float* __restrict__ A_log,
                                                 const float* __restrict__ Dp,
                                                 const float* __restrict__ initS,
                                                 bf16* __restrict__ y) {
    int d = blockIdx.x * 256 + threadIdx.x;
    int c = blockIdx.y;
    int b = blockIdx.z;
    __shared__ float BCs[CL][2 * D_STATE];
    for (int i = threadIdx.x; i < CL * 2 * D_STATE; i += 256) {
        int l = i >> 5, n = i & 31;
        BCs[l][n] = dbl[((size_t)b * SEQLEN + c * CL + l) * 96 + DT_RANK + n];
    }
    __syncthreads();
    float A[D_STATE];
    #pragma unroll
    for (int n = 0; n < D_STATE; ++n) A[n] = -expf(A_log[d * D_STATE + n]);
    float bias = dt_bias[d];
    float Dv = Dp[d];
    float st[D_STATE];
    #pragma unroll
    for (int n = 0; n < D_STATE; ++n)
        st[n] = initS[(((size_t)b * NC + c) * D_STATE + n) * D_INNER + d];
    for (int l = 0; l < CL; ++l) {
        size_t t = (size_t)b * SEQLEN + c * CL + l;
        float dtv = softplusf(dtp[t * D_INNER + d] + bias);
        float xcv = xc[t * D_INNER + d];
        float dx = dtv * xcv;
        float acc = 0.f;
        #pragma unroll
        for (int n = 0; n < D_STATE; ++n) {
            float a = expf(dtv * A[n]);
            st[n] = a * st[n] + dx * BCs[l][n];
            acc += st[n] * BCs[l][D_STATE + n];
        }
        acc += xcv * Dv;
        float zv = xz[t * (2 * D_INNER) + D_INNER + d];
        float sz = zv / (1.0f + expf(-zv));
        y[t * D_INNER + d] = __float2bfloat16(acc * sz);
    }
}

extern "C" void kernel_launch(void* const* d_in, const int* in_sizes, int n_in,
                              void* d_out, int out_size, void* d_ws, size_t ws_size,
                              hipStream_t stream) {
    const int*   x          = (const int*)  d_in[0];
    const float* emb        = (const float*)d_in[1];
    const float* norm_w     = (const float*)d_in[2];
    const float* in_proj_w  = (const float*)d_in[3];
    const float* conv_w     = (const float*)d_in[4];
    const float* conv_b     = (const float*)d_in[5];
    const float* x_proj_w   = (const float*)d_in[6];
    const float* dt_proj_w  = (const float*)d_in[7];
    const float* dt_bias    = (const float*)d_in[8];
    const float* A_log      = (const float*)d_in[9];
    const float* Dp         = (const float*)d_in[10];
    const float* out_proj_w = (const float*)d_in[11];
    const float* fnorm_w    = (const float*)d_in[12];
    float* out = (float*)d_out;

    // ---- d_out scratch layout (all dead before vocab GEMM writes logits) ----
    float* xz   = out;                   // [2048][4096]
    float* xc_f = out + 8388608;         // [2048][2048]
    float* dtp  = out + 12582912;        // [2048][2048]
    float* h    = out + 16777216;        // [2048][1024]
    float* dblf = out + 18874368;        // [2048][96]
    bf16* y_b    = (bf16*)(out + 19070976);  // [2048][2048] bf16
    bf16* xc_b   = (bf16*)(out + 21168128);  // [2048][2048] bf16
    bf16* dbl_b  = (bf16*)(out + 23265280);  // [2048][96]   bf16
    bf16* inpj_b = (bf16*)(out + 23363584);  // [2][4096][1024] bf16
    bf16* xpj_b  = (bf16*)(out + 27557888);  // [2][128][2048]  bf16
    bf16* dtpj_b = (bf16*)(out + 27820032);  // [2][2048][64]   bf16
    bf16* otpj_b = (bf16*)(out + 27951104);  // [2][1024][2048] bf16
    float* aprod = out + 30048256;       // [2][32][16][2048] = 2,097,152 f
    float* sfin  = out + 32145408;       // same
    float* initS = out + 34242560;       // same; ends 36,339,712 < 65,536,000

    // ---- ws layout ----
    bf16* embc_b = (bf16*)d_ws;                  // [4096][1024] bf16 chunk
    bf16* u_b    = (bf16*)d_ws + 4194304;        // [2048][1024] bf16

    f32_to_bf16<<<(2*2*D_INNER*D_MODEL/4 + 255)/256, 256, 0, stream>>>(in_proj_w,  inpj_b, 2*2*D_INNER*D_MODEL);
    conv_xproj_pad<<<dim3(D_INNER/256, 128, N_LAYER), 256, 0, stream>>>(x_proj_w, xpj_b);
    f32_to_bf16<<<(2*D_INNER*DT_RANK/4 + 255)/256, 256, 0, stream>>>(dt_proj_w,  dtpj_b, 2*D_INNER*DT_RANK);
    f32_to_bf16<<<(2*D_MODEL*D_INNER/4 + 255)/256, 256, 0, stream>>>(out_proj_w, otpj_b, 2*D_MODEL*D_INNER);

    embed_kernel<<<TOKENS, 256, 0, stream>>>(x, emb, h);

    for (int layer = 0; layer < N_LAYER; ++layer) {
        rmsnorm_bf16<<<TOKENS, 256, 0, stream>>>(h, norm_w + layer * D_MODEL, u_b);
        gemm_bf16<<<dim3(4096/128, TOKENS/128), 256, 0, stream>>>(
            u_b, D_MODEL, inpj_b + (size_t)layer * 2 * D_INNER * D_MODEL, D_MODEL,
            xz, 2 * D_INNER, 2 * D_INNER, D_MODEL, 0);
        conv_silu_kernel<<<dim3(D_INNER/256, SEQLEN, BATCH), 256, 0, stream>>>(
            xz, conv_w + (size_t)layer * D_INNER * D_CONV, conv_b + layer * D_INNER,
            xc_f, xc_b);
        gemm_bf16<<<dim3(1, TOKENS/128), 256, 0, stream>>>(
            xc_b, D_INNER, xpj_b + (size_t)layer * 128 * D_INNER, D_INNER,
            dblf, 96, 96, D_INNER, 0);
        f32_to_bf16<<<(TOKENS*96/4 + 255)/256, 256, 0, stream>>>(dblf, dbl_b, TOKENS*96);
        gemm_bf16<<<dim3(D_INNER/128, TOKENS/128), 256, 0, stream>>>(
            dbl_b, 96, dtpj_b + (size_t)layer * D_INNER * DT_RANK, DT_RANK,
            dtp, D_INNER, D_INNER, DT_RANK, 0);
        scan_chunk<<<dim3(D_INNER/256, NC, BATCH), 256, 0, stream>>>(
            dtp, dt_bias + layer * D_INNER, dblf, xc_f,
            A_log + (size_t)layer * D_INNER * D_STATE, aprod, sfin);
        scan_carry<<<(BATCH*D_STATE*D_INNER)/256, 256, 0, stream>>>(aprod, sfin, initS);
        scan_emit<<<dim3(D_INNER/256, NC, BATCH), 256, 0, stream>>>(
            dtp, dt_bias + layer * D_INNER, dblf, xc_f, xz,
            A_log + (size_t)layer * D_INNER * D_STATE, Dp + layer * D_INNER,
            initS, y_b);
        gemm_bf16<<<dim3(D_MODEL/128, TOKENS/128), 256, 0, stream>>>(
            y_b, D_INNER, otpj_b + (size_t)layer * D_MODEL * D_INNER, D_INNER,
            h, D_MODEL, D_MODEL, D_INNER, 1);
    }

    rmsnorm_bf16<<<TOKENS, 256, 0, stream>>>(h, fnorm_w, u_b);

    int n0 = 0;
    while (n0 < VOCAB) {
        int chunk = (VOCAB - n0 >= 4096) ? 4096 : (VOCAB - n0);
        f32_to_bf16<<<(chunk*D_MODEL/4 + 255)/256, 256, 0, stream>>>(
            emb + (size_t)n0 * D_MODEL, embc_b, chunk * D_MODEL);
        gemm_bf16<<<dim3(chunk/128, TOKENS/128), 256, 0, stream>>>(
            u_b, D_MODEL, embc_b, D_MODEL,
            out + n0, VOCAB, chunk, D_MODEL, 0);
        n0 += chunk;
    }
}

// Round 4
// 642.455 us; speedup vs baseline: 13.8452x; 1.4656x over previous
//
#include <hip/hip_runtime.h>
#include <hip/hip_bf16.h>
#include <math.h>

#define D_MODEL 1024
#define N_LAYER 2
#define D_STATE 16
#define D_CONV  4
#define D_INNER 2048
#define DT_RANK 64
#define VOCAB   32000
#define BATCH   2
#define SEQLEN  1024
#define TOKENS  (BATCH*SEQLEN)   // 2048
#define NC      32               // scan chunks
#define CL      32               // steps per chunk (SEQLEN/NC)

typedef __hip_bfloat16 bf16;
typedef __bf16 bf16x8 __attribute__((ext_vector_type(8)));
typedef float f32x4 __attribute__((ext_vector_type(4)));

__device__ inline void gld_lds16(const bf16* g, bf16* l) {
    __builtin_amdgcn_global_load_lds(
        (const __attribute__((address_space(1))) void*)g,
        (__attribute__((address_space(3))) void*)l, 16, 0, 0);
}

__device__ inline float softplus_fast(float v) {
    return (v > 20.f) ? v : __logf(1.f + __expf(v));
}
__device__ inline float silu_fast(float v) {
    return v / (1.f + __expf(-v));
}

// ---------------- embedding gather ----------------
__global__ __launch_bounds__(256) void embed_kernel(const int* __restrict__ x,
                                                    const float* __restrict__ emb,
                                                    float* __restrict__ h) {
    int t = blockIdx.x;
    int tok = x[t];
    const float4* src = (const float4*)(emb + (size_t)tok * D_MODEL);
    float4* dst = (float4*)(h + (size_t)t * D_MODEL);
    dst[threadIdx.x] = src[threadIdx.x];
}

// ---------------- rmsnorm -> bf16 output ----------------
__global__ __launch_bounds__(256) void rmsnorm_bf16(const float* __restrict__ h,
                                                    const float* __restrict__ w,
                                                    bf16* __restrict__ u) {
    int t = blockIdx.x;
    const float4* hv = (const float4*)(h + (size_t)t * D_MODEL);
    float4 v = hv[threadIdx.x];
    float ss = v.x*v.x + v.y*v.y + v.z*v.z + v.w*v.w;
    #pragma unroll
    for (int off = 32; off > 0; off >>= 1) ss += __shfl_down(ss, off);
    __shared__ float red[4];
    int lane = threadIdx.x & 63, wid = threadIdx.x >> 6;
    if (lane == 0) red[wid] = ss;
    __syncthreads();
    float tot = red[0] + red[1] + red[2] + red[3];
    float scale = rsqrtf(tot * (1.0f / (float)D_MODEL) + 1e-5f);
    float4 wq = ((const float4*)w)[threadIdx.x];
    size_t o = (size_t)t * D_MODEL + threadIdx.x * 4;
    u[o+0] = __float2bfloat16(v.x * scale * wq.x);
    u[o+1] = __float2bfloat16(v.y * scale * wq.y);
    u[o+2] = __float2bfloat16(v.z * scale * wq.z);
    u[o+3] = __float2bfloat16(v.w * scale * wq.w);
}

// ---------------- f32 -> bf16 convert (n multiple of 4) ----------------
__global__ __launch_bounds__(256) void f32_to_bf16(const float* __restrict__ s,
                                                   bf16* __restrict__ d, int n) {
    int i = (blockIdx.x * 256 + threadIdx.x) * 4;
    if (i < n) {
        float4 v = *(const float4*)(s + i);
        d[i+0] = __float2bfloat16(v.x);
        d[i+1] = __float2bfloat16(v.y);
        d[i+2] = __float2bfloat16(v.z);
        d[i+3] = __float2bfloat16(v.w);
    }
}

// ---------------- x_proj weight: [96][2048] -> padded bf16 [128][2048] ----------------
__global__ __launch_bounds__(256) void conv_xproj_pad(const float* __restrict__ s,
                                                      bf16* __restrict__ d) {
    int col = blockIdx.x * 256 + threadIdx.x;
    int row = blockIdx.y;
    int layer = blockIdx.z;
    float v = (row < 96) ? s[((size_t)layer * 96 + row) * D_INNER + col] : 0.f;
    d[((size_t)layer * 128 + row) * D_INNER + col] = __float2bfloat16(v);
}

// ---------------- bf16 MFMA GEMM: C[M,N] (+)= A[M,K] * W[N,K]^T ----------------
// 128x128 tile, BK=32, 4 waves (2x2), 64x64/wave. K mult of 32; rows of A/W
// 16B-aligned. Stores guarded by col<N (W rows past N must be readable).
// kSplit>1: blockIdx.z selects a K-slice of length K; A/W advanced by z*K,
// C written to partial slice z (C + z*M*ldc).
// swz!=0: XCD swizzle for the vocab grid (gridDim.x==256, gridDim.y==16).
__global__ __launch_bounds__(256) void gemm_bf16(
    const bf16* __restrict__ A, int lda,
    const bf16* __restrict__ W, int ldw,
    float* __restrict__ C, int ldc,
    int N, int K, int acc, int swz, int M)
{
    __shared__ bf16 As[128*32];
    __shared__ bf16 Bs[128*32];
    int bx = blockIdx.x, by = blockIdx.y;
    if (swz) {
        int bid = by * gridDim.x + bx;
        int k = bid & 7, j = bid >> 3;       // 8 XCDs; j in [0,512)
        bx = k * 32 + (j >> 4);              // 32 col-tiles per XCD
        by = j & 15;                          // 16 row-tiles
    }
    const int z = blockIdx.z;
    A += (size_t)z * K;
    W += (size_t)z * K;
    C += (size_t)z * M * (size_t)ldc;

    const int tid  = threadIdx.x;
    const int wave = tid >> 6;
    const int lane = tid & 63;
    const int wr = wave >> 1, wc = wave & 1;
    const size_t rowBase = (size_t)by * 128;
    const size_t colBase = (size_t)bx * 128;

    const int l4 = lane >> 2;
    const int k8 = (lane & 3) << 3;

    const bf16* aG0 = A + (rowBase + 32*wave      + l4) * (size_t)lda + k8;
    const bf16* aG1 = A + (rowBase + 32*wave + 16 + l4) * (size_t)lda + k8;
    const bf16* bG0 = W + (colBase + 32*wave      + l4) * (size_t)ldw + k8;
    const bf16* bG1 = W + (colBase + 32*wave + 16 + l4) * (size_t)ldw + k8;
    bf16* AsW = As + wave * 1024;
    bf16* BsW = Bs + wave * 1024;

    f32x4 accv[4][4];
    #pragma unroll
    for (int i = 0; i < 4; ++i)
        #pragma unroll
        for (int j = 0; j < 4; ++j)
            accv[i][j] = f32x4{0.f, 0.f, 0.f, 0.f};

    const int arow = wr*64 + (lane & 15);
    const int brow = wc*64 + (lane & 15);
    const int koff = (lane >> 4) << 3;
    const bf16* Ard = As + arow*32 + koff;
    const bf16* Brd = Bs + brow*32 + koff;

    for (int k0 = 0; k0 < K; k0 += 32) {
        gld_lds16(aG0 + k0, AsW);
        gld_lds16(aG1 + k0, AsW + 512);
        gld_lds16(bG0 + k0, BsW);
        gld_lds16(bG1 + k0, BsW + 512);
        __syncthreads();
        bf16x8 af[4], bv[4];
        #pragma unroll
        for (int i = 0; i < 4; ++i) af[i] = *(const bf16x8*)(Ard + i*16*32);
        #pragma unroll
        for (int j = 0; j < 4; ++j) bv[j] = *(const bf16x8*)(Brd + j*16*32);
        #pragma unroll
        for (int i = 0; i < 4; ++i)
            #pragma unroll
            for (int j = 0; j < 4; ++j)
                accv[i][j] = __builtin_amdgcn_mfma_f32_16x16x32_bf16(af[i], bv[j], accv[i][j], 0, 0, 0);
        __syncthreads();
    }

    const int cl = lane & 15;
    const int rg = (lane >> 4) * 4;
    #pragma unroll
    for (int i = 0; i < 4; ++i) {
        #pragma unroll
        for (int j = 0; j < 4; ++j) {
            int col = (int)colBase + wc*64 + j*16 + cl;
            if (col < N) {
                size_t base = (rowBase + wr*64 + i*16 + rg) * (size_t)ldc + col;
                #pragma unroll
                for (int r = 0; r < 4; ++r) {
                    size_t idx = base + (size_t)r * ldc;
                    C[idx] = acc ? C[idx] + accv[i][j][r] : accv[i][j][r];
                }
            }
        }
    }
}

// ---------------- causal depthwise conv (k=4) + bias + silu, 8 l per thread ----
__global__ __launch_bounds__(256) void conv_silu_kernel(const float* __restrict__ xz,
                                                        const float* __restrict__ cw,
                                                        const float* __restrict__ cb,
                                                        float* __restrict__ xcf,
                                                        bf16* __restrict__ xcb) {
    int d = blockIdx.x * 256 + threadIdx.x;
    int l0 = blockIdx.y * 8;
    int b = blockIdx.z;
    float w0 = cw[d*4+0], w1 = cw[d*4+1], w2 = cw[d*4+2], w3 = cw[d*4+3];
    float bias = cb[d];
    float win0 = (l0 >= 3) ? xz[((size_t)b * SEQLEN + l0 - 3) * (2*D_INNER) + d] : 0.f;
    float win1 = (l0 >= 2) ? xz[((size_t)b * SEQLEN + l0 - 2) * (2*D_INNER) + d] : 0.f;
    float win2 = (l0 >= 1) ? xz[((size_t)b * SEQLEN + l0 - 1) * (2*D_INNER) + d] : 0.f;
    #pragma unroll
    for (int i = 0; i < 8; ++i) {
        float cur = xz[((size_t)b * SEQLEN + l0 + i) * (2*D_INNER) + d];
        float acc = bias + w0*win0 + w1*win1 + w2*win2 + w3*cur;
        float s = silu_fast(acc);
        size_t o = ((size_t)b * SEQLEN + l0 + i) * D_INNER + d;
        xcf[o] = s;
        xcb[o] = __float2bfloat16(s);
        win0 = win1; win1 = win2; win2 = cur;
    }
}

// ---------------- x_proj split-K reduce: sum 8 partials -> f32 + bf16 ----------------
__global__ __launch_bounds__(256) void reduce_xproj(const float* __restrict__ px,
                                                    float* __restrict__ dblf,
                                                    bf16* __restrict__ dbl_b) {
    int i = blockIdx.x * 256 + threadIdx.x;  // t*96+n
    float s = 0.f;
    #pragma unroll
    for (int z = 0; z < 8; ++z) s += px[(size_t)z * (TOKENS*96) + i];
    dblf[i] = s;
    dbl_b[i] = __float2bfloat16(s);
}

// ---------------- out_proj split-K reduce: h += p0 + p1 ----------------
__global__ __launch_bounds__(256) void reduce_oproj(const float* __restrict__ po,
                                                    float* __restrict__ h) {
    int i = (blockIdx.x * 256 + threadIdx.x) * 4;
    float4 a = *(const float4*)(po + i);
    float4 b = *(const float4*)(po + (size_t)TOKENS*D_MODEL + i);
    float4 hv = *(const float4*)(h + i);
    hv.x += a.x + b.x; hv.y += a.y + b.y; hv.z += a.z + b.z; hv.w += a.w + b.w;
    *(float4*)(h + i) = hv;
}

// ---------------- scan phase A: per-chunk summaries (zero init) ----------------
__global__ __launch_bounds__(256) void scan_chunk(const float* __restrict__ dtp,
                                                  const float* __restrict__ dt_bias,
                                                  const float* __restrict__ dbl,
                                                  const float* __restrict__ xc,
                                                  const float* __restrict__ A_log,
                                                  float* __restrict__ aprod,
                                                  float* __restrict__ sfin) {
    int d = blockIdx.x * 256 + threadIdx.x;
    int c = blockIdx.y;
    int b = blockIdx.z;
    __shared__ float Bs[CL][D_STATE];
    for (int i = threadIdx.x; i < CL * D_STATE; i += 256) {
        int l = i >> 4, n = i & 15;
        Bs[l][n] = dbl[((size_t)b * SEQLEN + c * CL + l) * 96 + DT_RANK + n];
    }
    __syncthreads();
    float A[D_STATE];
    #pragma unroll
    for (int n = 0; n < D_STATE; ++n) A[n] = -__expf(A_log[d * D_STATE + n]);
    float bias = dt_bias[d];
    float st[D_STATE];
    #pragma unroll
    for (int n = 0; n < D_STATE; ++n) st[n] = 0.f;
    float dts = 0.f;
    for (int l = 0; l < CL; ++l) {
        size_t t = (size_t)b * SEQLEN + c * CL + l;
        float dtv = softplus_fast(dtp[t * D_INNER + d] + bias);
        dts += dtv;
        float dx = dtv * xc[t * D_INNER + d];
        #pragma unroll
        for (int n = 0; n < D_STATE; ++n) {
            float a = __expf(dtv * A[n]);
            st[n] = a * st[n] + dx * Bs[l][n];
        }
    }
    #pragma unroll
    for (int n = 0; n < D_STATE; ++n) {
        size_t o = (((size_t)b * NC + c) * D_STATE + n) * D_INNER + d;
        aprod[o] = __expf(dts * A[n]);   // prod over chunk = exp of dt-sum
        sfin[o] = st[n];
    }
}

// ---------------- scan phase B: carry chunk-initial states ----------------
__global__ __launch_bounds__(256) void scan_carry(const float* __restrict__ aprod,
                                                  const float* __restrict__ sfin,
                                                  float* __restrict__ initS) {
    int idx = blockIdx.x * 256 + threadIdx.x;
    int d = idx & (D_INNER - 1);
    int n = (idx >> 11) & (D_STATE - 1);
    int b = idx >> 15;
    float st = 0.f;
    for (int c = 0; c < NC; ++c) {
        size_t o = (((size_t)b * NC + c) * D_STATE + n) * D_INNER + d;
        initS[o] = st;
        st = aprod[o] * st + sfin[o];
    }
}

// ---------------- scan phase C: recompute with true init, emit gated y ----------------
__global__ __launch_bounds__(256) void scan_emit(const float* __restrict__ dtp,
                                                 const float* __restrict__ dt_bias,
                                                 const float* __restrict__ dbl,
                                                 const float* __restrict__ xc,
                                                 const float* __restrict__ xz,
                                                 const float* __restrict__ A_log,
                                                 const float* __restrict__ Dp,
                                                 const float* __restrict__ initS,
                                                 bf16* __restrict__ y) {
    int d = blockIdx.x * 256 + threadIdx.x;
    int c = blockIdx.y;
    int b = blockIdx.z;
    __shared__ float BCs[CL][2 * D_STATE];
    for (int i = threadIdx.x; i < CL * 2 * D_STATE; i += 256) {
        int l = i >> 5, n = i & 31;
        BCs[l][n] = dbl[((size_t)b * SEQLEN + c * CL + l) * 96 + DT_RANK + n];
    }
    __syncthreads();
    float A[D_STATE];
    #pragma unroll
    for (int n = 0; n < D_STATE; ++n) A[n] = -__expf(A_log[d * D_STATE + n]);
    float bias = dt_bias[d];
    float Dv = Dp[d];
    float st[D_STATE];
    #pragma unroll
    for (int n = 0; n < D_STATE; ++n)
        st[n] = initS[(((size_t)b * NC + c) * D_STATE + n) * D_INNER + d];
    for (int l = 0; l < CL; ++l) {
        size_t t = (size_t)b * SEQLEN + c * CL + l;
        float dtv = softplus_fast(dtp[t * D_INNER + d] + bias);
        float xcv = xc[t * D_INNER + d];
        float dx = dtv * xcv;
        float acc = 0.f;
        #pragma unroll
        for (int n = 0; n < D_STATE; ++n) {
            float a = __expf(dtv * A[n]);
            st[n] = a * st[n] + dx * BCs[l][n];
            acc += st[n] * BCs[l][D_STATE + n];
        }
        acc += xcv * Dv;
        float zv = xz[t * (2 * D_INNER) + D_INNER + d];
        y[t * D_INNER + d] = __float2bfloat16(acc * silu_fast(zv));
    }
}

extern "C" void kernel_launch(void* const* d_in, const int* in_sizes, int n_in,
                              void* d_out, int out_size, void* d_ws, size_t ws_size,
                              hipStream_t stream) {
    const int*   x          = (const int*)  d_in[0];
    const float* emb        = (const float*)d_in[1];
    const float* norm_w     = (const float*)d_in[2];
    const float* in_proj_w  = (const float*)d_in[3];
    const float* conv_w     = (const float*)d_in[4];
    const float* conv_b     = (const float*)d_in[5];
    const float* x_proj_w   = (const float*)d_in[6];
    const float* dt_proj_w  = (const float*)d_in[7];
    const float* dt_bias    = (const float*)d_in[8];
    const float* A_log      = (const float*)d_in[9];
    const float* Dp         = (const float*)d_in[10];
    const float* out_proj_w = (const float*)d_in[11];
    const float* fnorm_w    = (const float*)d_in[12];
    float* out = (float*)d_out;
    float* ws  = (float*)d_ws;

    // ---- ws scratch layout (floats; harness fill shows ws ~1000 MiB; ~238 MB used)
    bf16*  embf   = (bf16*)ws;              // [32000][1024] bf16
    bf16*  u_b    = (bf16*)(ws + 16384000); // [2048][1024] bf16
    float* xz     = ws + 17432576;          // [2048][4096]
    float* xc_f   = ws + 25821184;          // [2048][2048]
    bf16*  xc_b   = (bf16*)(ws + 30015488); // [2048][2048] bf16
    float* dtp    = ws + 32112640;          // [2048][2048]
    float* h      = ws + 36306944;          // [2048][1024]
    float* dblf   = ws + 38404096;          // [2048][96]
    bf16*  dbl_b  = (bf16*)(ws + 38600704); // [2048][96] bf16
    bf16*  y_b    = (bf16*)(ws + 38699008); // [2048][2048] bf16
    bf16*  inpj_b = (bf16*)(ws + 40796160); // [2][4096][1024] bf16
    bf16*  xpj_b  = (bf16*)(ws + 44990464); // [2][128][2048] bf16
    bf16*  dtpj_b = (bf16*)(ws + 45252608); // [2][2048][64] bf16
    bf16*  otpj_b = (bf16*)(ws + 45383680); // [2][1024][2048] bf16
    float* aprod  = ws + 47480832;          // [2][32][16][2048]
    float* sfin   = ws + 49577984;
    float* initS  = ws + 51675136;
    float* px     = ws + 53772288;          // [8][2048][96]
    float* po     = ws + 55345152;          // [2][2048][1024]

    f32_to_bf16<<<(VOCAB*D_MODEL/4 + 255)/256, 256, 0, stream>>>(emb, embf, VOCAB*D_MODEL);
    f32_to_bf16<<<(2*2*D_INNER*D_MODEL/4 + 255)/256, 256, 0, stream>>>(in_proj_w,  inpj_b, 2*2*D_INNER*D_MODEL);
    conv_xproj_pad<<<dim3(D_INNER/256, 128, N_LAYER), 256, 0, stream>>>(x_proj_w, xpj_b);
    f32_to_bf16<<<(2*D_INNER*DT_RANK/4 + 255)/256, 256, 0, stream>>>(dt_proj_w,  dtpj_b, 2*D_INNER*DT_RANK);
    f32_to_bf16<<<(2*D_MODEL*D_INNER/4 + 255)/256, 256, 0, stream>>>(out_proj_w, otpj_b, 2*D_MODEL*D_INNER);

    embed_kernel<<<TOKENS, 256, 0, stream>>>(x, emb, h);

    for (int layer = 0; layer < N_LAYER; ++layer) {
        rmsnorm_bf16<<<TOKENS, 256, 0, stream>>>(h, norm_w + layer * D_MODEL, u_b);
        gemm_bf16<<<dim3(4096/128, TOKENS/128), 256, 0, stream>>>(
            u_b, D_MODEL, inpj_b + (size_t)layer * 2 * D_INNER * D_MODEL, D_MODEL,
            xz, 2 * D_INNER, 2 * D_INNER, D_MODEL, 0, 0, TOKENS);
        conv_silu_kernel<<<dim3(D_INNER/256, SEQLEN/8, BATCH), 256, 0, stream>>>(
            xz, conv_w + (size_t)layer * D_INNER * D_CONV, conv_b + layer * D_INNER,
            xc_f, xc_b);
        // x_proj: split-K 8 via grid.z (K=256 per slice), then reduce (+bf16 cvt)
        gemm_bf16<<<dim3(1, TOKENS/128, 8), 256, 0, stream>>>(
            xc_b, D_INNER, xpj_b + (size_t)layer * 128 * D_INNER, D_INNER,
            px, 96, 96, 256, 0, 0, TOKENS);
        reduce_xproj<<<(TOKENS*96)/256, 256, 0, stream>>>(px, dblf, dbl_b);
        gemm_bf16<<<dim3(D_INNER/128, TOKENS/128), 256, 0, stream>>>(
            dbl_b, 96, dtpj_b + (size_t)layer * D_INNER * DT_RANK, DT_RANK,
            dtp, D_INNER, D_INNER, DT_RANK, 0, 0, TOKENS);
        scan_chunk<<<dim3(D_INNER/256, NC, BATCH), 256, 0, stream>>>(
            dtp, dt_bias + layer * D_INNER, dblf, xc_f,
            A_log + (size_t)layer * D_INNER * D_STATE, aprod, sfin);
        scan_carry<<<(BATCH*D_STATE*D_INNER)/256, 256, 0, stream>>>(aprod, sfin, initS);
        scan_emit<<<dim3(D_INNER/256, NC, BATCH), 256, 0, stream>>>(
            dtp, dt_bias + layer * D_INNER, dblf, xc_f, xz,
            A_log + (size_t)layer * D_INNER * D_STATE, Dp + layer * D_INNER,
            initS, y_b);
        // out_proj: split-K 2 via grid.z (K=1024 per slice), then h += p0+p1
        gemm_bf16<<<dim3(D_MODEL/128, TOKENS/128, 2), 256, 0, stream>>>(
            y_b, D_INNER, otpj_b + (size_t)layer * D_MODEL * D_INNER, D_INNER,
            po, D_MODEL, D_MODEL, 1024, 0, 0, TOKENS);
        reduce_oproj<<<(TOKENS*D_MODEL/4)/256, 256, 0, stream>>>(po, h);
    }

    rmsnorm_bf16<<<TOKENS, 256, 0, stream>>>(h, fnorm_w, u_b);

    // vocab GEMM: single launch, col grid padded to 256 tiles, XCD swizzle.
    // (Blocks with colBase >= 32000 read W rows past emb's 32000 — these land
    //  inside ws (allocated), and their stores are fully guarded by col<N.)
    gemm_bf16<<<dim3(256, TOKENS/128), 256, 0, stream>>>(
        u_b, D_MODEL, embf, D_MODEL,
        out, VOCAB, VOCAB, D_MODEL, 0, 1, TOKENS);
}

// Round 5
// 547.425 us; speedup vs baseline: 16.2487x; 1.1736x over previous
//
#include <hip/hip_runtime.h>
#include <hip/hip_bf16.h>
#include <math.h>

#define D_MODEL 1024
#define N_LAYER 2
#define D_STATE 16
#define D_CONV  4
#define D_INNER 2048
#define DT_RANK 64
#define VOCAB   32000
#define BATCH   2
#define SEQLEN  1024
#define TOKENS  (BATCH*SEQLEN)   // 2048
#define NC      32               // scan chunks
#define CL      32               // steps per chunk (SEQLEN/NC)

typedef __hip_bfloat16 bf16;
typedef __bf16 bf16x8 __attribute__((ext_vector_type(8)));
typedef float f32x4 __attribute__((ext_vector_type(4)));

__device__ inline void gld_lds16(const bf16* g, bf16* l) {
    __builtin_amdgcn_global_load_lds(
        (const __attribute__((address_space(1))) void*)g,
        (__attribute__((address_space(3))) void*)l, 16, 0, 0);
}

__device__ inline float softplus_fast(float v) {
    return (v > 20.f) ? v : __logf(1.f + __expf(v));
}
__device__ inline float silu_fast(float v) {
    return v / (1.f + __expf(-v));
}

// ---------------- embedding gather ----------------
__global__ __launch_bounds__(256) void embed_kernel(const int* __restrict__ x,
                                                    const float* __restrict__ emb,
                                                    float* __restrict__ h) {
    int t = blockIdx.x;
    int tok = x[t];
    const float4* src = (const float4*)(emb + (size_t)tok * D_MODEL);
    float4* dst = (float4*)(h + (size_t)t * D_MODEL);
    dst[threadIdx.x] = src[threadIdx.x];
}

// ---------------- rmsnorm -> bf16 output ----------------
__global__ __launch_bounds__(256) void rmsnorm_bf16(const float* __restrict__ h,
                                                    const float* __restrict__ w,
                                                    bf16* __restrict__ u) {
    int t = blockIdx.x;
    const float4* hv = (const float4*)(h + (size_t)t * D_MODEL);
    float4 v = hv[threadIdx.x];
    float ss = v.x*v.x + v.y*v.y + v.z*v.z + v.w*v.w;
    #pragma unroll
    for (int off = 32; off > 0; off >>= 1) ss += __shfl_down(ss, off);
    __shared__ float red[4];
    int lane = threadIdx.x & 63, wid = threadIdx.x >> 6;
    if (lane == 0) red[wid] = ss;
    __syncthreads();
    float tot = red[0] + red[1] + red[2] + red[3];
    float scale = rsqrtf(tot * (1.0f / (float)D_MODEL) + 1e-5f);
    float4 wq = ((const float4*)w)[threadIdx.x];
    size_t o = (size_t)t * D_MODEL + threadIdx.x * 4;
    u[o+0] = __float2bfloat16(v.x * scale * wq.x);
    u[o+1] = __float2bfloat16(v.y * scale * wq.y);
    u[o+2] = __float2bfloat16(v.z * scale * wq.z);
    u[o+3] = __float2bfloat16(v.w * scale * wq.w);
}

// ---------------- f32 -> bf16 convert (n multiple of 4) ----------------
__global__ __launch_bounds__(256) void f32_to_bf16(const float* __restrict__ s,
                                                   bf16* __restrict__ d, int n) {
    int i = (blockIdx.x * 256 + threadIdx.x) * 4;
    if (i < n) {
        float4 v = *(const float4*)(s + i);
        d[i+0] = __float2bfloat16(v.x);
        d[i+1] = __float2bfloat16(v.y);
        d[i+2] = __float2bfloat16(v.z);
        d[i+3] = __float2bfloat16(v.w);
    }
}

// ---------------- x_proj weight: [96][2048] -> padded bf16 [128][2048] ----------------
__global__ __launch_bounds__(256) void conv_xproj_pad(const float* __restrict__ s,
                                                      bf16* __restrict__ d) {
    int col = blockIdx.x * 256 + threadIdx.x;
    int row = blockIdx.y;
    int layer = blockIdx.z;
    float v = (row < 96) ? s[((size_t)layer * 96 + row) * D_INNER + col] : 0.f;
    d[((size_t)layer * 128 + row) * D_INNER + col] = __float2bfloat16(v);
}

// ---------------- bf16 MFMA GEMM: C[M,N] (+)= A[M,K] * W[N,K]^T ----------------
// 128x128 tile, BK=64, double-buffered LDS (64KB), T2 XOR-swizzle, counted
// vmcnt(8) pipeline (tile t+1's 8 loads stay in flight across the barrier).
// 4 waves (2x2), 64x64 per wave, 16x16x32 MFMA.
// Requirements: M,K mult of 128/64; A/W rows 16B-aligned; W must have
// >= gridDim.x*128 readable rows (stores guarded by col < N).
// z (blockIdx.z): K-split slice — A,W advanced by z*K, C -> slice z.
// swz: bijective XCD swizzle (requires gridDim.x*gridDim.y % 8 == 0).
__global__ __launch_bounds__(256) void gemm_bf16(
    const bf16* __restrict__ A, int lda,
    const bf16* __restrict__ W, int ldw,
    float* __restrict__ C, int ldc,
    int N, int K, int acc, int swz, int M)
{
    __shared__ bf16 lds[2][2][128 * 64];   // [buf][A/B][row*64 + swizzled col]
    int bx = blockIdx.x, by = blockIdx.y;
    if (swz) {
        int bid = by * gridDim.x + bx;
        int q = (gridDim.x * gridDim.y) >> 3;
        int n = (bid & 7) * q + (bid >> 3);
        by = n % gridDim.y;              // consecutive n share the B-panel
        bx = n / gridDim.y;
    }
    const int z = blockIdx.z;
    A += (size_t)z * K;
    W += (size_t)z * K;
    C += (size_t)z * M * (size_t)ldc;

    const int tid  = threadIdx.x;
    const int wave = tid >> 6;
    const int lane = tid & 63;
    const int wr = wave >> 1, wc = wave & 1;
    const size_t rowBase = (size_t)by * 128;
    const size_t colBase = (size_t)bx * 128;

    // --- staging addressing (T2: linear LDS dest, pre-swizzled global src) ---
    // round i (0..3): wave stages rows 32i+8*wave .. +7 (8 rows x 128B = 1KB).
    // lane -> row sub (lane>>3), global col 8*((lane&7) ^ (lane>>3)) so that
    // LDS[row][cs] = G[row][cs ^ 8*(row&7)].
    const int srow = 8 * wave + (lane >> 3);
    const int scol = ((lane & 7) ^ (lane >> 3)) << 3;
    const bf16* aGs = A + (rowBase + srow) * (size_t)lda + scol;
    const bf16* bGs = W + (colBase + srow) * (size_t)ldw + scol;

#define STAGE(tt, bb) do {                                                      \
        const size_t kofs_ = (size_t)(tt) * 64;                                 \
        _Pragma("unroll")                                                       \
        for (int i_ = 0; i_ < 4; ++i_) {                                        \
            gld_lds16(aGs + kofs_ + (size_t)(32 * i_) * lda,                    \
                      &lds[bb][0][(32 * i_ + 8 * wave) * 64]);                  \
            gld_lds16(bGs + kofs_ + (size_t)(32 * i_) * ldw,                    \
                      &lds[bb][1][(32 * i_ + 8 * wave) * 64]);                  \
        }                                                                       \
    } while (0)

    f32x4 accv[4][4];
    #pragma unroll
    for (int i = 0; i < 4; ++i)
        #pragma unroll
        for (int j = 0; j < 4; ++j)
            accv[i][j] = f32x4{0.f, 0.f, 0.f, 0.f};

    const int arow0 = wr * 64 + (lane & 15);
    const int brow0 = wc * 64 + (lane & 15);
    const int h8  = (lane >> 4) << 3;     // k element offset within 32-slice
    const int sw8 = (lane & 7) << 3;      // swizzle key (elements)

    const int NT = K >> 6;
    STAGE(0, 0);
    for (int t = 0; t < NT; ++t) {
        const int cur = t & 1;
        if (t + 1 < NT) {
            STAGE(t + 1, cur ^ 1);
            asm volatile("s_waitcnt vmcnt(8)" ::: "memory");   // tile t landed
        } else {
            asm volatile("s_waitcnt vmcnt(0)" ::: "memory");
        }
        __builtin_amdgcn_s_barrier();

        const bf16* Ab = &lds[cur][0][0];
        const bf16* Bb = &lds[cur][1][0];
        #pragma unroll
        for (int kk = 0; kk < 2; ++kk) {
            const int cs = ((kk << 5) + h8) ^ sw8;
            bf16x8 af[4], bv[4];
            #pragma unroll
            for (int i = 0; i < 4; ++i)
                af[i] = *(const bf16x8*)(Ab + (arow0 + 16 * i) * 64 + cs);
            #pragma unroll
            for (int j = 0; j < 4; ++j)
                bv[j] = *(const bf16x8*)(Bb + (brow0 + 16 * j) * 64 + cs);
            #pragma unroll
            for (int i = 0; i < 4; ++i)
                #pragma unroll
                for (int j = 0; j < 4; ++j)
                    accv[i][j] = __builtin_amdgcn_mfma_f32_16x16x32_bf16(
                        af[i], bv[j], accv[i][j], 0, 0, 0);
        }
        asm volatile("s_waitcnt lgkmcnt(0)" ::: "memory");     // reads retired
        __builtin_amdgcn_s_barrier();                          // slot reusable
    }
#undef STAGE

    const int cl = lane & 15;
    const int rg = (lane >> 4) * 4;
    #pragma unroll
    for (int i = 0; i < 4; ++i) {
        #pragma unroll
        for (int j = 0; j < 4; ++j) {
            int col = (int)colBase + wc * 64 + j * 16 + cl;
            if (col < N) {
                size_t base = (rowBase + wr * 64 + i * 16 + rg) * (size_t)ldc + col;
                #pragma unroll
                for (int r = 0; r < 4; ++r) {
                    size_t idx = base + (size_t)r * ldc;
                    C[idx] = acc ? C[idx] + accv[i][j][r] : accv[i][j][r];
                }
            }
        }
    }
}

// ---------------- causal depthwise conv (k=4) + bias + silu, 8 l per thread ----
__global__ __launch_bounds__(256) void conv_silu_kernel(const float* __restrict__ xz,
                                                        const float* __restrict__ cw,
                                                        const float* __restrict__ cb,
                                                        float* __restrict__ xcf,
                                                        bf16* __restrict__ xcb) {
    int d = blockIdx.x * 256 + threadIdx.x;
    int l0 = blockIdx.y * 8;
    int b = blockIdx.z;
    float w0 = cw[d*4+0], w1 = cw[d*4+1], w2 = cw[d*4+2], w3 = cw[d*4+3];
    float bias = cb[d];
    float win0 = (l0 >= 3) ? xz[((size_t)b * SEQLEN + l0 - 3) * (2*D_INNER) + d] : 0.f;
    float win1 = (l0 >= 2) ? xz[((size_t)b * SEQLEN + l0 - 2) * (2*D_INNER) + d] : 0.f;
    float win2 = (l0 >= 1) ? xz[((size_t)b * SEQLEN + l0 - 1) * (2*D_INNER) + d] : 0.f;
    #pragma unroll
    for (int i = 0; i < 8; ++i) {
        float cur = xz[((size_t)b * SEQLEN + l0 + i) * (2*D_INNER) + d];
        float acc = bias + w0*win0 + w1*win1 + w2*win2 + w3*cur;
        float s = silu_fast(acc);
        size_t o = ((size_t)b * SEQLEN + l0 + i) * D_INNER + d;
        xcf[o] = s;
        xcb[o] = __float2bfloat16(s);
        win0 = win1; win1 = win2; win2 = cur;
    }
}

// ---------------- x_proj split-K reduce: sum 8 partials -> f32 + bf16 ----------------
__global__ __launch_bounds__(256) void reduce_xproj(const float* __restrict__ px,
                                                    float* __restrict__ dblf,
                                                    bf16* __restrict__ dbl_b) {
    int i = blockIdx.x * 256 + threadIdx.x;
    float s = 0.f;
    #pragma unroll
    for (int z = 0; z < 8; ++z) s += px[(size_t)z * (TOKENS*96) + i];
    dblf[i] = s;
    dbl_b[i] = __float2bfloat16(s);
}

// ---------------- out_proj split-K reduce: h += p0 + p1 ----------------
__global__ __launch_bounds__(256) void reduce_oproj(const float* __restrict__ po,
                                                    float* __restrict__ h) {
    int i = (blockIdx.x * 256 + threadIdx.x) * 4;
    float4 a = *(const float4*)(po + i);
    float4 b = *(const float4*)(po + (size_t)TOKENS*D_MODEL + i);
    float4 hv = *(const float4*)(h + i);
    hv.x += a.x + b.x; hv.y += a.y + b.y; hv.z += a.z + b.z; hv.w += a.w + b.w;
    *(float4*)(h + i) = hv;
}

// ---------------- scan phase A: per-chunk summaries (zero init) ----------------
__global__ __launch_bounds__(256) void scan_chunk(const float* __restrict__ dtp,
                                                  const float* __restrict__ dt_bias,
                                                  const float* __restrict__ dbl,
                                                  const float* __restrict__ xc,
                                                  const float* __restrict__ A_log,
                                                  float* __restrict__ aprod,
                                                  float* __restrict__ sfin) {
    int d = blockIdx.x * 256 + threadIdx.x;
    int c = blockIdx.y;
    int b = blockIdx.z;
    __shared__ float Bs[CL][D_STATE];
    for (int i = threadIdx.x; i < CL * D_STATE; i += 256) {
        int l = i >> 4, n = i & 15;
        Bs[l][n] = dbl[((size_t)b * SEQLEN + c * CL + l) * 96 + DT_RANK + n];
    }
    __syncthreads();
    float A[D_STATE];
    #pragma unroll
    for (int n = 0; n < D_STATE; ++n) A[n] = -__expf(A_log[d * D_STATE + n]);
    float bias = dt_bias[d];
    float st[D_STATE];
    #pragma unroll
    for (int n = 0; n < D_STATE; ++n) st[n] = 0.f;
    float dts = 0.f;
    for (int l = 0; l < CL; ++l) {
        size_t t = (size_t)b * SEQLEN + c * CL + l;
        float dtv = softplus_fast(dtp[t * D_INNER + d] + bias);
        dts += dtv;
        float dx = dtv * xc[t * D_INNER + d];
        #pragma unroll
        for (int n = 0; n < D_STATE; ++n) {
            float a = __expf(dtv * A[n]);
            st[n] = a * st[n] + dx * Bs[l][n];
        }
    }
    #pragma unroll
    for (int n = 0; n < D_STATE; ++n) {
        size_t o = (((size_t)b * NC + c) * D_STATE + n) * D_INNER + d;
        aprod[o] = __expf(dts * A[n]);   // prod over chunk = exp of dt-sum
        sfin[o] = st[n];
    }
}

// ---------------- scan phase B: carry chunk-initial states ----------------
__global__ __launch_bounds__(256) void scan_carry(const float* __restrict__ aprod,
                                                  const float* __restrict__ sfin,
                                                  float* __restrict__ initS) {
    int idx = blockIdx.x * 256 + threadIdx.x;
    int d = idx & (D_INNER - 1);
    int n = (idx >> 11) & (D_STATE - 1);
    int b = idx >> 15;
    float st = 0.f;
    for (int c = 0; c < NC; ++c) {
        size_t o = (((size_t)b * NC + c) * D_STATE + n) * D_INNER + d;
        initS[o] = st;
        st = aprod[o] * st + sfin[o];
    }
}

// ---------------- scan phase C: recompute with true init, emit gated y ----------------
__global__ __launch_bounds__(256) void scan_emit(const float* __restrict__ dtp,
                                                 const float* __restrict__ dt_bias,
                                                 const float* __restrict__ dbl,
                                                 const float* __restrict__ xc,
                                                 const float* __restrict__ xz,
                                                 const float* __restrict__ A_log,
                                                 const float* __restrict__ Dp,
                                                 const float* __restrict__ initS,
                                                 bf16* __restrict__ y) {
    int d = blockIdx.x * 256 + threadIdx.x;
    int c = blockIdx.y;
    int b = blockIdx.z;
    __shared__ float BCs[CL][2 * D_STATE];
    for (int i = threadIdx.x; i < CL * 2 * D_STATE; i += 256) {
        int l = i >> 5, n = i & 31;
        BCs[l][n] = dbl[((size_t)b * SEQLEN + c * CL + l) * 96 + DT_RANK + n];
    }
    __syncthreads();
    float A[D_STATE];
    #pragma unroll
    for (int n = 0; n < D_STATE; ++n) A[n] = -__expf(A_log[d * D_STATE + n]);
    float bias = dt_bias[d];
    float Dv = Dp[d];
    float st[D_STATE];
    #pragma unroll
    for (int n = 0; n < D_STATE; ++n)
        st[n] = initS[(((size_t)b * NC + c) * D_STATE + n) * D_INNER + d];
    for (int l = 0; l < CL; ++l) {
        size_t t = (size_t)b * SEQLEN + c * CL + l;
        float dtv = softplus_fast(dtp[t * D_INNER + d] + bias);
        float xcv = xc[t * D_INNER + d];
        float dx = dtv * xcv;
        float acc = 0.f;
        #pragma unroll
        for (int n = 0; n < D_STATE; ++n) {
            float a = __expf(dtv * A[n]);
            st[n] = a * st[n] + dx * BCs[l][n];
            acc += st[n] * BCs[l][D_STATE + n];
        }
        acc += xcv * Dv;
        float zv = xz[t * (2 * D_INNER) + D_INNER + d];
        y[t * D_INNER + d] = __float2bfloat16(acc * silu_fast(zv));
    }
}

extern "C" void kernel_launch(void* const* d_in, const int* in_sizes, int n_in,
                              void* d_out, int out_size, void* d_ws, size_t ws_size,
                              hipStream_t stream) {
    const int*   x          = (const int*)  d_in[0];
    const float* emb        = (const float*)d_in[1];
    const float* norm_w     = (const float*)d_in[2];
    const float* in_proj_w  = (const float*)d_in[3];
    const float* conv_w     = (const float*)d_in[4];
    const float* conv_b     = (const float*)d_in[5];
    const float* x_proj_w   = (const float*)d_in[6];
    const float* dt_proj_w  = (const float*)d_in[7];
    const float* dt_bias    = (const float*)d_in[8];
    const float* A_log      = (const float*)d_in[9];
    const float* Dp         = (const float*)d_in[10];
    const float* out_proj_w = (const float*)d_in[11];
    const float* fnorm_w    = (const float*)d_in[12];
    float* out = (float*)d_out;
    float* ws  = (float*)d_ws;

    // ---- ws scratch layout ----
    bf16*  embf   = (bf16*)ws;              // [32000][1024] bf16
    bf16*  u_b    = (bf16*)(ws + 16384000); // [2048][1024] bf16
    float* xz     = ws + 17432576;          // [2048][4096]
    float* xc_f   = ws + 25821184;          // [2048][2048]
    bf16*  xc_b   = (bf16*)(ws + 30015488); // [2048][2048] bf16
    float* dtp    = ws + 32112640;          // [2048][2048]
    float* h      = ws + 36306944;          // [2048][1024]
    float* dblf   = ws + 38404096;          // [2048][96]
    bf16*  dbl_b  = (bf16*)(ws + 38600704); // [2048][96] bf16
    bf16*  y_b    = (bf16*)(ws + 38699008); // [2048][2048] bf16
    bf16*  inpj_b = (bf16*)(ws + 40796160); // [2][4096][1024] bf16
    bf16*  xpj_b  = (bf16*)(ws + 44990464); // [2][128][2048] bf16
    bf16*  dtpj_b = (bf16*)(ws + 45252608); // [2][2048][64] bf16
    bf16*  otpj_b = (bf16*)(ws + 45383680); // [2][1024][2048] bf16
    float* aprod  = ws + 47480832;          // [2][32][16][2048]
    float* sfin   = ws + 49577984;
    float* initS  = ws + 51675136;
    float* px     = ws + 53772288;          // [8][2048][96]
    float* po     = ws + 55345152;          // [2][2048][1024]

    f32_to_bf16<<<(VOCAB*D_MODEL/4 + 255)/256, 256, 0, stream>>>(emb, embf, VOCAB*D_MODEL);
    f32_to_bf16<<<(2*2*D_INNER*D_MODEL/4 + 255)/256, 256, 0, stream>>>(in_proj_w,  inpj_b, 2*2*D_INNER*D_MODEL);
    conv_xproj_pad<<<dim3(D_INNER/256, 128, N_LAYER), 256, 0, stream>>>(x_proj_w, xpj_b);
    f32_to_bf16<<<(2*D_INNER*DT_RANK/4 + 255)/256, 256, 0, stream>>>(dt_proj_w,  dtpj_b, 2*D_INNER*DT_RANK);
    f32_to_bf16<<<(2*D_MODEL*D_INNER/4 + 255)/256, 256, 0, stream>>>(out_proj_w, otpj_b, 2*D_MODEL*D_INNER);

    embed_kernel<<<TOKENS, 256, 0, stream>>>(x, emb, h);

    for (int layer = 0; layer < N_LAYER; ++layer) {
        rmsnorm_bf16<<<TOKENS, 256, 0, stream>>>(h, norm_w + layer * D_MODEL, u_b);
        gemm_bf16<<<dim3(4096/128, TOKENS/128), 256, 0, stream>>>(
            u_b, D_MODEL, inpj_b + (size_t)layer * 2 * D_INNER * D_MODEL, D_MODEL,
            xz, 2 * D_INNER, 2 * D_INNER, D_MODEL, 0, 1, TOKENS);
        conv_silu_kernel<<<dim3(D_INNER/256, SEQLEN/8, BATCH), 256, 0, stream>>>(
            xz, conv_w + (size_t)layer * D_INNER * D_CONV, conv_b + layer * D_INNER,
            xc_f, xc_b);
        // x_proj: split-K 8 via grid.z (K=256 per slice), then reduce (+bf16 cvt)
        gemm_bf16<<<dim3(1, TOKENS/128, 8), 256, 0, stream>>>(
            xc_b, D_INNER, xpj_b + (size_t)layer * 128 * D_INNER, D_INNER,
            px, 96, 96, 256, 0, 0, TOKENS);
        reduce_xproj<<<(TOKENS*96)/256, 256, 0, stream>>>(px, dblf, dbl_b);
        gemm_bf16<<<dim3(D_INNER/128, TOKENS/128), 256, 0, stream>>>(
            dbl_b, 96, dtpj_b + (size_t)layer * D_INNER * DT_RANK, DT_RANK,
            dtp, D_INNER, D_INNER, DT_RANK, 0, 1, TOKENS);
        scan_chunk<<<dim3(D_INNER/256, NC, BATCH), 256, 0, stream>>>(
            dtp, dt_bias + layer * D_INNER, dblf, xc_f,
            A_log + (size_t)layer * D_INNER * D_STATE, aprod, sfin);
        scan_carry<<<(BATCH*D_STATE*D_INNER)/256, 256, 0, stream>>>(aprod, sfin, initS);
        scan_emit<<<dim3(D_INNER/256, NC, BATCH), 256, 0, stream>>>(
            dtp, dt_bias + layer * D_INNER, dblf, xc_f, xz,
            A_log + (size_t)layer * D_INNER * D_STATE, Dp + layer * D_INNER,
            initS, y_b);
        // out_proj: split-K 2 via grid.z (K=1024 per slice), then h += p0+p1
        gemm_bf16<<<dim3(D_MODEL/128, TOKENS/128, 2), 256, 0, stream>>>(
            y_b, D_INNER, otpj_b + (size_t)layer * D_MODEL * D_INNER, D_INNER,
            po, D_MODEL, D_MODEL, 1024, 0, 1, TOKENS);
        reduce_oproj<<<(TOKENS*D_MODEL/4)/256, 256, 0, stream>>>(po, h);
    }

    rmsnorm_bf16<<<TOKENS, 256, 0, stream>>>(h, fnorm_w, u_b);

    // vocab GEMM: 250x16 tiles (32000 = 250*128, exact), bijective XCD swizzle
    gemm_bf16<<<dim3(VOCAB/128, TOKENS/128), 256, 0, stream>>>(
        u_b, D_MODEL, embf, D_MODEL,
        out, VOCAB, VOCAB, D_MODEL, 0, 1, TOKENS);
}